// Round 12
// baseline (291.525 us; speedup 1.0000x reference)
//
#include <hip/hip_runtime.h>

#define N_NODES 4096
#define C_CH    128
#define E_ELEM  10
#define NP      4736          // padded sorted-node space (64-aligned per element)
#define TT      219           // 9 deg1 + 45 deg2 + 165 deg3 monomials
#define PSTRIDE (TT * 4)      // 876 floats per (e,c): [t][m], m0=L0, m1..3=L1
#define MAXCHUNK 32
#define CHUNK_J  512          // j-slots per k_poly block (256 thr x 2 nodes)

// ws layout (bytes):
#define WS_CHE     256
#define WS_CHJ     512
#define WS_CHEND   768
#define WS_JLIST   1024        // int[4736]
#define WS_ELEM    20480       // int[4096]
#define WS_S31     53248       // float[3465]
#define WS_S30     67136       // float[825]
#define WS_S21     70464       // float[405]
#define WS_S20     72128       // float[90]
#define WS_P       72704       // float[1280*876] = 4485120 B
#define WS_BOUT    4557824     // float[512*4736] = 9699328 B
#define WS_XS      14257152    // float[128*4736*9] = 21823488 B
#define WS_XS_END  36080640ull

__device__ __forceinline__ void t3_decode(int t, int& a, int& b, int& i) {
    int cnt = 0;
    for (int aa = 0; aa < 9; ++aa)
        for (int bb = aa; bb < 9; ++bb) {
            int len = 9 - bb;
            if (t < cnt + len) { a = aa; b = bb; i = bb + (t - cnt); return; }
            cnt += len;
        }
    a = b = i = 8;
}

__device__ __forceinline__ void t2_decode(int t, int& a, int& b) {
    int cnt = 0;
    for (int aa = 0; aa < 9; ++aa) {
        int len = 9 - aa;
        if (t < cnt + len) { a = aa; b = aa + (t - cnt); return; }
        cnt += len;
    }
    a = b = 8;
}

// Fused front (R10 shape, proven): blocks 0-18 symmetrize U; blocks 19-34
// decode elem across CUs (R11's single-block fusion serialized the 160 KB
// cold attrs read onto one CU -> 54.6 us; this spread form was in the
// 91.7 us config).
__global__ __launch_bounds__(256) void k_front(
    const float* __restrict__ attrs, int* __restrict__ elem,
    const float* __restrict__ U3_1, const float* __restrict__ U3_0,
    const float* __restrict__ U2_1, const float* __restrict__ U2_0,
    float* __restrict__ S31, float* __restrict__ S30,
    float* __restrict__ S21, float* __restrict__ S20) {
    int bid = blockIdx.x;
    if (bid >= 19) {
        int n = (bid - 19) * 256 + threadIdx.x;
        if (n >= N_NODES) return;
        const float* a = attrs + n * E_ELEM;
        float best = a[0];
        int e = 0;
#pragma unroll
        for (int k = 1; k < E_ELEM; ++k) {
            float v = a[k];
            if (v > best) { best = v; e = k; }
        }
        elem[n] = e;
        return;
    }
    int q = bid * 256 + threadIdx.x;
    if (q < 3465) {                                 // S31 [m][t][p], p=7
        int m = q / 1155, r = q % 1155, t = r / 7, p = r % 7;
        int a, b, i;
        t3_decode(t, a, b, i);
#define U31(X, Y, Z) U3_1[((((m * 9 + (X)) * 9 + (Y)) * 9 + (Z)) * 7) + p]
        float s = U31(a, b, i);
        if (a == b && b == i) {}
        else if (a == b) s += U31(a, i, a) + U31(i, a, a);
        else if (b == i) s += U31(b, a, b) + U31(b, b, a);
        else s += U31(a, i, b) + U31(b, a, i) + U31(b, i, a) + U31(i, a, b) + U31(i, b, a);
#undef U31
        S31[q] = s;
        return;
    }
    q -= 3465;
    if (q < 825) {                                  // S30 [t][p], p=5
        int t = q / 5, p = q % 5;
        int a, b, i;
        t3_decode(t, a, b, i);
#define U30(X, Y, Z) U3_0[((((X) * 9 + (Y)) * 9 + (Z)) * 5) + p]
        float s = U30(a, b, i);
        if (a == b && b == i) {}
        else if (a == b) s += U30(a, i, a) + U30(i, a, a);
        else if (b == i) s += U30(b, a, b) + U30(b, b, a);
        else s += U30(a, i, b) + U30(b, a, i) + U30(b, i, a) + U30(i, a, b) + U30(i, b, a);
#undef U30
        S30[q] = s;
        return;
    }
    q -= 825;
    if (q < 405) {                                  // S21 [m][t][p], p=3
        int m = q / 135, r = q % 135, t = r / 3, p = r % 3;
        int a, b;
        t2_decode(t, a, b);
        float s = U2_1[(((m * 9 + a) * 9 + b) * 3) + p];
        if (a != b) s += U2_1[(((m * 9 + b) * 9 + a) * 3) + p];
        S21[q] = s;
        return;
    }
    q -= 405;
    if (q < 90) {                                   // S20 [t][p], p=2
        int t = q / 2, p = q % 2;
        int a, b;
        t2_decode(t, a, b);
        float s = U2_0[((a * 9 + b) * 2) + p];
        if (a != b) s += U2_0[((b * 9 + a) * 2) + p];
        S20[q] = s;
    }
}

// Single-block sort (R10 shape, proven): LDS histogram -> prefix -> chunk
// table -> jlist pad-fill -> LDS-cursor scatter. Reads L2-hot elem[].
__global__ __launch_bounds__(1024) void k_sort(
    const int* __restrict__ elem, int* __restrict__ jlist,
    int* __restrict__ chE, int* __restrict__ chJ, int* __restrict__ chEnd) {
    __shared__ int h[E_ELEM];
    __shared__ int cur[E_ELEM];
    int tid = threadIdx.x;
    if (tid < E_ELEM) h[tid] = 0;
    __syncthreads();
    for (int n = tid; n < N_NODES; n += 1024) atomicAdd(&h[elem[n]], 1);
    for (int p = tid; p < NP; p += 1024) jlist[p] = -1;
    __syncthreads();
    if (tid == 0) {
        int ps[E_ELEM + 1];
        int s = 0;
        for (int e = 0; e < E_ELEM; ++e) {
            ps[e] = s;
            cur[e] = s;
            s += ((h[e] + 63) >> 6) << 6;        // 64-align each element range
        }
        ps[E_ELEM] = s;
        int ci = 0;
        for (int e = 0; e < E_ELEM; ++e) {
            for (int ofs = ps[e]; ofs < ps[e + 1]; ofs += CHUNK_J) {
                chE[ci] = e;
                chJ[ci] = ofs;
                chEnd[ci] = ps[e + 1];
                ++ci;
            }
        }
        for (; ci < MAXCHUNK; ++ci) chE[ci] = -1;
    }
    __syncthreads();
    for (int n = tid; n < N_NODES; n += 1024) {
        int e = elem[n];
        int pos = atomicAdd(&cur[e], 1);
        jlist[pos] = n;
    }
}

// Fused mid: blocks <1280 fold P[e,c]; blocks >=1280 transpose x into sorted
// j-space (gather reads / coalesced writes). Pad j -> 0.
__global__ __launch_bounds__(256) void k_mid(
    const float* __restrict__ S31, const float* __restrict__ S30,
    const float* __restrict__ S21, const float* __restrict__ S20,
    const float* __restrict__ U1_1, const float* __restrict__ U1_0,
    const float* __restrict__ W3_1, const float* __restrict__ W3_0,
    const float* __restrict__ W2_1, const float* __restrict__ W2_0,
    const float* __restrict__ W1_1, const float* __restrict__ W1_0,
    float* __restrict__ P,
    const float* __restrict__ x, const int* __restrict__ jlist,
    float* __restrict__ xs) {
    int bid = blockIdx.x;
    if (bid >= 1280) {
        int t = (bid - 1280) * 256 + threadIdx.x;   // [0, 128*4736*9) exact
        int i = t % 9;
        int r = t / 9;
        int j = r % NP;
        int c = r / NP;
        int n = jlist[j];
        xs[t] = (n >= 0) ? x[((size_t)n * C_CH + c) * 9 + i] : 0.f;
        return;
    }
    int e = bid >> 7;
    int c = bid & 127;
    float* Pout = P + (size_t)bid * PSTRIDE;
    for (int q = threadIdx.x; q < PSTRIDE; q += 256) {
        int t = q >> 2, m = q & 3;
        float v;
        if (t < 9) {
            int a = t;
            v = (m == 0) ? U1_0[a] * W1_0[e * C_CH + c]
                         : U1_1[(m - 1) * 9 + a] * W1_1[e * C_CH + c];
        } else if (t < 54) {
            int t2 = t - 9;
            float s = 0.f;
            if (m == 0) {
#pragma unroll
                for (int p = 0; p < 2; ++p)
                    s = fmaf(S20[t2 * 2 + p], W2_0[(e * 2 + p) * C_CH + c], s);
            } else {
#pragma unroll
                for (int p = 0; p < 3; ++p)
                    s = fmaf(S21[((m - 1) * 45 + t2) * 3 + p], W2_1[(e * 3 + p) * C_CH + c], s);
            }
            v = s;
        } else {
            int t3 = t - 54;
            float s = 0.f;
            if (m == 0) {
#pragma unroll
                for (int p = 0; p < 5; ++p)
                    s = fmaf(S30[t3 * 5 + p], W3_0[(e * 5 + p) * C_CH + c], s);
            } else {
#pragma unroll
                for (int p = 0; p < 7; ++p)
                    s = fmaf(S31[((m - 1) * 165 + t3) * 7 + p], W3_1[(e * 7 + p) * C_CH + c], s);
            }
            v = s;
        }
        Pout[q] = v;
    }
}

// 219-monomial cubic, LDS-staged coefficients + NN=2.
// Why this combo (R11 post-mortem): coefficient DELIVERY is the bottleneck,
// not VALU (floor 9.2 us). s_load variant = 45 serialized scalar-latency
// regions/wave (58.9 us at NN=2). LDS broadcast is throughput-bound instead:
// 5120 waves x 219 ds_read_b128 x 12 cyc / 256 CUs ~= 22 us, and NN=2 is
// what halves that pipe cost per output. sched_barrier(0) per (a,b) group
// bounds in-flight float4s (R2's hoist->256 VGPR spill). Live ~40 VGPR.
__device__ __forceinline__ void poly_eval2(const float* __restrict__ sP,
                                           const float (&xv)[2][9], float (&acc)[2][4]) {
    const float* p1 = sP;
    const float* p2 = sP + 9 * 4;
    const float* p3 = sP + 54 * 4;
    int i2 = 0, i3 = 0;
#pragma unroll
    for (int a = 0; a < 9; ++a) {
        float4 q1 = *(const float4*)(p1 + a * 4);
#pragma unroll
        for (int u = 0; u < 2; ++u) {
            float xa = xv[u][a];
            acc[u][0] = fmaf(q1.x, xa, acc[u][0]);
            acc[u][1] = fmaf(q1.y, xa, acc[u][1]);
            acc[u][2] = fmaf(q1.z, xa, acc[u][2]);
            acc[u][3] = fmaf(q1.w, xa, acc[u][3]);
        }
        __builtin_amdgcn_sched_barrier(0);
#pragma unroll
        for (int b = a; b < 9; ++b) {
            float4 q2 = *(const float4*)(p2 + i2 * 4);
            ++i2;
            float m2[2];
#pragma unroll
            for (int u = 0; u < 2; ++u) {
                m2[u] = xv[u][a] * xv[u][b];
                acc[u][0] = fmaf(q2.x, m2[u], acc[u][0]);
                acc[u][1] = fmaf(q2.y, m2[u], acc[u][1]);
                acc[u][2] = fmaf(q2.z, m2[u], acc[u][2]);
                acc[u][3] = fmaf(q2.w, m2[u], acc[u][3]);
            }
#pragma unroll
            for (int i = b; i < 9; ++i) {
                float4 q3 = *(const float4*)(p3 + i3 * 4);
                ++i3;
#pragma unroll
                for (int u = 0; u < 2; ++u) {
                    float m3 = m2[u] * xv[u][i];
                    acc[u][0] = fmaf(q3.x, m3, acc[u][0]);
                    acc[u][1] = fmaf(q3.y, m3, acc[u][1]);
                    acc[u][2] = fmaf(q3.z, m3, acc[u][2]);
                    acc[u][3] = fmaf(q3.w, m3, acc[u][3]);
                }
            }
            __builtin_amdgcn_sched_barrier(0);
        }
    }
}

__global__ __launch_bounds__(256) void k_poly(
    const float* __restrict__ xs, const int* __restrict__ chE,
    const int* __restrict__ chJ, const int* __restrict__ chEnd,
    const float* __restrict__ P, float* __restrict__ bout) {
    int ci = blockIdx.y;
    int e = chE[ci];
    if (e < 0) return;
    e = __builtin_amdgcn_readfirstlane(e);
    int c = blockIdx.x;
    __shared__ __align__(16) float sP[PSTRIDE];
    const float* __restrict__ Pg = P + (size_t)(e * C_CH + c) * PSTRIDE;
    for (int t = threadIdx.x; t < PSTRIDE; t += 256) sP[t] = Pg[t];
    __syncthreads();

    const int end = chEnd[ci];
    const int jA = chJ[ci] + threadIdx.x;
    const int jB = jA + 256;
    const bool vA = jA < end, vB = jB < end;
    if (!vA) return;

    float xv[2][9];
    const float* pA = xs + ((size_t)c * NP + jA) * 9;               // coalesced
    const float* pB = xs + ((size_t)c * NP + (vB ? jB : jA)) * 9;   // coalesced
#pragma unroll
    for (int i = 0; i < 9; ++i) { xv[0][i] = pA[i]; xv[1][i] = pB[i]; }
    float acc[2][4] = {};
    poly_eval2(sP, xv, acc);
#pragma unroll
    for (int m = 0; m < 4; ++m) bout[(size_t)(c * 4 + m) * NP + jA] = acc[0][m];
    if (vB) {
#pragma unroll
        for (int m = 0; m < 4; ++m) bout[(size_t)(c * 4 + m) * NP + jB] = acc[1][m];
    }
}

// j-lane GEMM (R10 shape, proven): grid (74,16) = 1184 blocks, D=8 d/thread
// via wave-uniform readfirstlane (s_load W), bv batched 32-deep (VGPR ~52).
__global__ __launch_bounds__(256) void k_linear(
    const float* __restrict__ bout, const int* __restrict__ jlist,
    const float* __restrict__ Wl0, const float* __restrict__ Wl1,
    const float* __restrict__ sc, float* __restrict__ out) {
    const int s  = blockIdx.y >> 2;
    const int dg = blockIdx.y & 3;
    const int jj = threadIdx.x & 63;
    const int wv = threadIdx.x >> 6;
    const int dbase = __builtin_amdgcn_readfirstlane(dg * 32 + wv * 8);
    const int j = blockIdx.x * 64 + jj;
    const float* __restrict__ Wl = (s == 0) ? Wl0 : Wl1;
    const float* __restrict__ brow = bout + (size_t)s * NP + j;

    float acc[8];
#pragma unroll
    for (int k = 0; k < 8; ++k) acc[k] = 0.f;

#pragma unroll 1
    for (int cc0 = 0; cc0 < C_CH; cc0 += 32) {
        float bv[32];
#pragma unroll
        for (int t = 0; t < 32; ++t)
            bv[t] = brow[(size_t)(cc0 + t) * 4 * NP];
#pragma unroll
        for (int t = 0; t < 32; ++t) {
            const float* wrow = Wl + (cc0 + t) * C_CH + dbase;  // scalar addr
#pragma unroll
            for (int k = 0; k < 8; ++k) acc[k] = fmaf(bv[t], wrow[k], acc[k]);
        }
    }

    const int n = jlist[j];
    if (n < 0) return;
    const float inv = 0.08838834764831845f;  // 1/sqrt(128)
#pragma unroll
    for (int k = 0; k < 8; ++k) {
        int d = dbase + k;
        int col = (s == 0) ? d : (128 + d * 3 + (s - 1));
        out[n * 512 + col] = fmaf(acc[k], inv, sc[n * 512 + col]);
    }
}

extern "C" void kernel_launch(void* const* d_in, const int* in_sizes, int n_in,
                              void* d_out, int out_size, void* d_ws, size_t ws_size,
                              hipStream_t stream) {
    const float* x     = (const float*)d_in[0];
    const float* sc    = (const float*)d_in[1];
    const float* attrs = (const float*)d_in[2];
    const float* U3_0 = (const float*)d_in[3];
    const float* U2_0 = (const float*)d_in[4];
    const float* U1_0 = (const float*)d_in[5];
    const float* W3_0 = (const float*)d_in[6];
    const float* W2_0 = (const float*)d_in[7];
    const float* W1_0 = (const float*)d_in[8];
    const float* Wl0  = (const float*)d_in[9];
    const float* U3_1 = (const float*)d_in[10];
    const float* U2_1 = (const float*)d_in[11];
    const float* U1_1 = (const float*)d_in[12];
    const float* W3_1 = (const float*)d_in[13];
    const float* W2_1 = (const float*)d_in[14];
    const float* W1_1 = (const float*)d_in[15];
    const float* Wl1  = (const float*)d_in[16];

    char* ws = (char*)d_ws;
    int* chE     = (int*)(ws + WS_CHE);
    int* chJ     = (int*)(ws + WS_CHJ);
    int* chEnd   = (int*)(ws + WS_CHEND);
    int* jlist   = (int*)(ws + WS_JLIST);
    int* elem    = (int*)(ws + WS_ELEM);
    float* S31   = (float*)(ws + WS_S31);
    float* S30   = (float*)(ws + WS_S30);
    float* S21   = (float*)(ws + WS_S21);
    float* S20   = (float*)(ws + WS_S20);
    float* P     = (float*)(ws + WS_P);
    float* bout  = (float*)(ws + WS_BOUT);
    float* xs    = (float*)(ws + WS_XS);

    // L1: sym + elem decode (spread across CUs)
    k_front<<<35, 256, 0, stream>>>(attrs, elem, U3_1, U3_0, U2_1, U2_0,
                                    S31, S30, S21, S20);
    // L2: hist + prefix + chunk table + pad fill + scatter (one block)
    k_sort<<<1, 1024, 0, stream>>>(elem, jlist, chE, chJ, chEnd);
    // L3: fold P  ||  transpose x -> xs (coalesced writes)
    k_mid<<<1280 + (C_CH * NP * 9) / 256, 256, 0, stream>>>(
        S31, S30, S21, S20, U1_1, U1_0, W3_1, W3_0, W2_1, W2_0, W1_1, W1_0,
        P, x, jlist, xs);
    // L4: 219-monomial cubic (LDS coefficients, 2 nodes/thread)
    k_poly<<<dim3(128, MAXCHUNK), 256, 0, stream>>>(xs, chE, chJ, chEnd, P, bout);
    // L5: channel-mixing linear + residual
    k_linear<<<dim3(NP / 64, 16), 256, 0, stream>>>(bout, jlist, Wl0, Wl1, sc,
                                                    (float*)d_out);
}

// Round 13
// 77.004 us; speedup vs baseline: 3.7858x; 3.7858x over previous
//
#include <hip/hip_runtime.h>

#define N_NODES 4096
#define C_CH    128
#define E_ELEM  10
#define NP      4736          // padded sorted-node space (64-aligned per element)
#define TT      219           // 9 deg1 + 45 deg2 + 165 deg3 monomials
#define PSTRIDE (TT * 4)      // 876 floats per (e,c): [t][m], m0=L0, m1..3=L1
#define MAXCHUNK 32
#define CHUNK_J  256          // j-slots per k_poly block (256 thr x 1 node)

// ws layout (bytes):
#define WS_CHE     256
#define WS_CHJ     512
#define WS_CHEND   768
#define WS_JLIST   1024        // int[4736]
#define WS_ELEM    20480       // int[4096]
#define WS_S31     53248       // float[3465]
#define WS_S30     67136       // float[825]
#define WS_S21     70464       // float[405]
#define WS_S20     72128       // float[90]
#define WS_P       72704       // float[1280*876] = 4485120 B
#define WS_BOUT    4557824     // float[512*4736] = 9699328 B

__device__ __forceinline__ void t3_decode(int t, int& a, int& b, int& i) {
    int cnt = 0;
    for (int aa = 0; aa < 9; ++aa)
        for (int bb = aa; bb < 9; ++bb) {
            int len = 9 - bb;
            if (t < cnt + len) { a = aa; b = bb; i = bb + (t - cnt); return; }
            cnt += len;
        }
    a = b = i = 8;
}

__device__ __forceinline__ void t2_decode(int t, int& a, int& b) {
    int cnt = 0;
    for (int aa = 0; aa < 9; ++aa) {
        int len = 9 - aa;
        if (t < cnt + len) { a = aa; b = aa + (t - cnt); return; }
        cnt += len;
    }
    a = b = 8;
}

// Fused front (R10 shape, proven): blocks 0-18 symmetrize U; blocks 19-34
// decode elem across CUs.
__global__ __launch_bounds__(256) void k_front(
    const float* __restrict__ attrs, int* __restrict__ elem,
    const float* __restrict__ U3_1, const float* __restrict__ U3_0,
    const float* __restrict__ U2_1, const float* __restrict__ U2_0,
    float* __restrict__ S31, float* __restrict__ S30,
    float* __restrict__ S21, float* __restrict__ S20) {
    int bid = blockIdx.x;
    if (bid >= 19) {
        int n = (bid - 19) * 256 + threadIdx.x;
        if (n >= N_NODES) return;
        const float* a = attrs + n * E_ELEM;
        float best = a[0];
        int e = 0;
#pragma unroll
        for (int k = 1; k < E_ELEM; ++k) {
            float v = a[k];
            if (v > best) { best = v; e = k; }
        }
        elem[n] = e;
        return;
    }
    int q = bid * 256 + threadIdx.x;
    if (q < 3465) {                                 // S31 [m][t][p], p=7
        int m = q / 1155, r = q % 1155, t = r / 7, p = r % 7;
        int a, b, i;
        t3_decode(t, a, b, i);
#define U31(X, Y, Z) U3_1[((((m * 9 + (X)) * 9 + (Y)) * 9 + (Z)) * 7) + p]
        float s = U31(a, b, i);
        if (a == b && b == i) {}
        else if (a == b) s += U31(a, i, a) + U31(i, a, a);
        else if (b == i) s += U31(b, a, b) + U31(b, b, a);
        else s += U31(a, i, b) + U31(b, a, i) + U31(b, i, a) + U31(i, a, b) + U31(i, b, a);
#undef U31
        S31[q] = s;
        return;
    }
    q -= 3465;
    if (q < 825) {                                  // S30 [t][p], p=5
        int t = q / 5, p = q % 5;
        int a, b, i;
        t3_decode(t, a, b, i);
#define U30(X, Y, Z) U3_0[((((X) * 9 + (Y)) * 9 + (Z)) * 5) + p]
        float s = U30(a, b, i);
        if (a == b && b == i) {}
        else if (a == b) s += U30(a, i, a) + U30(i, a, a);
        else if (b == i) s += U30(b, a, b) + U30(b, b, a);
        else s += U30(a, i, b) + U30(b, a, i) + U30(b, i, a) + U30(i, a, b) + U30(i, b, a);
#undef U30
        S30[q] = s;
        return;
    }
    q -= 825;
    if (q < 405) {                                  // S21 [m][t][p], p=3
        int m = q / 135, r = q % 135, t = r / 3, p = r % 3;
        int a, b;
        t2_decode(t, a, b);
        float s = U2_1[(((m * 9 + a) * 9 + b) * 3) + p];
        if (a != b) s += U2_1[(((m * 9 + b) * 9 + a) * 3) + p];
        S21[q] = s;
        return;
    }
    q -= 405;
    if (q < 90) {                                   // S20 [t][p], p=2
        int t = q / 2, p = q % 2;
        int a, b;
        t2_decode(t, a, b);
        float s = U2_0[((a * 9 + b) * 2) + p];
        if (a != b) s += U2_0[((b * 9 + a) * 2) + p];
        S20[q] = s;
    }
}

// Merged sort+fold (independent work, one dispatch): block 0 = R10's proven
// single-block sort (LDS hist -> prefix -> chunk table -> pad fill ->
// LDS-cursor scatter); blocks 1-1280 = P[e,c] fold. With the transpose
// eliminated (k_poly now gathers x directly) the fold no longer shares a
// launch with xs, so the pipeline is 4 dispatches total.
__global__ __launch_bounds__(1024) void k_sortfold(
    const int* __restrict__ elem, int* __restrict__ jlist,
    int* __restrict__ chE, int* __restrict__ chJ, int* __restrict__ chEnd,
    const float* __restrict__ S31, const float* __restrict__ S30,
    const float* __restrict__ S21, const float* __restrict__ S20,
    const float* __restrict__ U1_1, const float* __restrict__ U1_0,
    const float* __restrict__ W3_1, const float* __restrict__ W3_0,
    const float* __restrict__ W2_1, const float* __restrict__ W2_0,
    const float* __restrict__ W1_1, const float* __restrict__ W1_0,
    float* __restrict__ P) {
    const int bid = blockIdx.x;
    const int tid = threadIdx.x;
    if (bid == 0) {
        __shared__ int h[E_ELEM];
        __shared__ int cur[E_ELEM];
        if (tid < E_ELEM) h[tid] = 0;
        __syncthreads();
        for (int n = tid; n < N_NODES; n += 1024) atomicAdd(&h[elem[n]], 1);
        for (int p = tid; p < NP; p += 1024) jlist[p] = -1;
        __syncthreads();
        if (tid == 0) {
            int ps[E_ELEM + 1];
            int s = 0;
            for (int e = 0; e < E_ELEM; ++e) {
                ps[e] = s;
                cur[e] = s;
                s += ((h[e] + 63) >> 6) << 6;    // 64-align each element range
            }
            ps[E_ELEM] = s;
            int ci = 0;
            for (int e = 0; e < E_ELEM; ++e) {
                for (int ofs = ps[e]; ofs < ps[e + 1]; ofs += CHUNK_J) {
                    chE[ci] = e;
                    chJ[ci] = ofs;
                    chEnd[ci] = ps[e + 1];
                    ++ci;
                }
            }
            for (; ci < MAXCHUNK; ++ci) chE[ci] = -1;
        }
        __syncthreads();
        for (int n = tid; n < N_NODES; n += 1024) {
            int e = elem[n];
            int pos = atomicAdd(&cur[e], 1);
            jlist[pos] = n;
        }
        return;
    }
    // fold blocks: (e,c) = bid-1
    int fb = bid - 1;
    int e = fb >> 7;
    int c = fb & 127;
    float* Pout = P + (size_t)fb * PSTRIDE;
    for (int q = tid; q < PSTRIDE; q += 1024) {
        int t = q >> 2, m = q & 3;
        float v;
        if (t < 9) {
            int a = t;
            v = (m == 0) ? U1_0[a] * W1_0[e * C_CH + c]
                         : U1_1[(m - 1) * 9 + a] * W1_1[e * C_CH + c];
        } else if (t < 54) {
            int t2 = t - 9;
            float s = 0.f;
            if (m == 0) {
#pragma unroll
                for (int p = 0; p < 2; ++p)
                    s = fmaf(S20[t2 * 2 + p], W2_0[(e * 2 + p) * C_CH + c], s);
            } else {
#pragma unroll
                for (int p = 0; p < 3; ++p)
                    s = fmaf(S21[((m - 1) * 45 + t2) * 3 + p], W2_1[(e * 3 + p) * C_CH + c], s);
            }
            v = s;
        } else {
            int t3 = t - 54;
            float s = 0.f;
            if (m == 0) {
#pragma unroll
                for (int p = 0; p < 5; ++p)
                    s = fmaf(S30[t3 * 5 + p], W3_0[(e * 5 + p) * C_CH + c], s);
            } else {
#pragma unroll
                for (int p = 0; p < 7; ++p)
                    s = fmaf(S31[((m - 1) * 165 + t3) * 7 + p], W3_1[(e * 7 + p) * C_CH + c], s);
            }
            v = s;
        }
        Pout[q] = v;
    }
}

// 219-monomial cubic — EXACT R10 shape (s_load coefficients, NN=1,
// sched_barrier(0) per (a,b) group). Never spilled (VGPR 24, SGPR 112).
// NN=2 is poison in any delivery form (R11: latency; R3/R4/R12: 0.5-1.9 GB
// RA spill) — do not revisit.
__device__ __forceinline__ void poly_eval1(const float* __restrict__ sP,
                                           const float (&xv)[9], float (&acc)[4]) {
    const float* p1 = sP;
    const float* p2 = sP + 9 * 4;
    const float* p3 = sP + 54 * 4;
    int i2 = 0, i3 = 0;
#pragma unroll
    for (int a = 0; a < 9; ++a) {
        float4 q1 = *(const float4*)(p1 + a * 4);
        float xa = xv[a];
        acc[0] = fmaf(q1.x, xa, acc[0]);
        acc[1] = fmaf(q1.y, xa, acc[1]);
        acc[2] = fmaf(q1.z, xa, acc[2]);
        acc[3] = fmaf(q1.w, xa, acc[3]);
        __builtin_amdgcn_sched_barrier(0);
#pragma unroll
        for (int b = a; b < 9; ++b) {
            float4 q2 = *(const float4*)(p2 + i2 * 4);
            ++i2;
            float m2 = xv[a] * xv[b];
            acc[0] = fmaf(q2.x, m2, acc[0]);
            acc[1] = fmaf(q2.y, m2, acc[1]);
            acc[2] = fmaf(q2.z, m2, acc[2]);
            acc[3] = fmaf(q2.w, m2, acc[3]);
#pragma unroll
            for (int i = b; i < 9; ++i) {
                float4 q3 = *(const float4*)(p3 + i3 * 4);
                ++i3;
                float m3 = m2 * xv[i];
                acc[0] = fmaf(q3.x, m3, acc[0]);
                acc[1] = fmaf(q3.y, m3, acc[1]);
                acc[2] = fmaf(q3.z, m3, acc[2]);
                acc[3] = fmaf(q3.w, m3, acc[3]);
            }
            __builtin_amdgcn_sched_barrier(0);
        }
    }
}

// Transpose eliminated (R12 post-mortem mechanism): read x directly via
// jlist gather — each thread loads its 36 B row (L1 merges the 9 dwords);
// pays the ~2.6x gather overfetch ONCE instead of transpose-write 19 MB +
// coalesced re-read 22 MB. Pad j -> skip entirely (k_linear masks).
__global__ __launch_bounds__(256) void k_poly(
    const float* __restrict__ x, const int* __restrict__ jlist,
    const int* __restrict__ chE, const int* __restrict__ chJ,
    const int* __restrict__ chEnd, const float* __restrict__ P,
    float* __restrict__ bout) {
    int ci = blockIdx.y;
    int e = chE[ci];
    if (e < 0) return;
    e = __builtin_amdgcn_readfirstlane(e);
    int c = blockIdx.x;
    const float* __restrict__ Pg = P + (size_t)(e * C_CH + c) * PSTRIDE;

    const int end = chEnd[ci];
    const int j = chJ[ci] + threadIdx.x;
    if (j >= end) return;
    const int n = jlist[j];
    if (n < 0) return;

    float xv[9];
    const float* px = x + ((size_t)n * C_CH + c) * 9;
#pragma unroll
    for (int i = 0; i < 9; ++i) xv[i] = px[i];
    float acc[4] = {};
    poly_eval1(Pg, xv, acc);
#pragma unroll
    for (int m = 0; m < 4; ++m) bout[(size_t)(c * 4 + m) * NP + j] = acc[m];
}

// j-lane GEMM (R10 shape, proven): grid (74,16) = 1184 blocks, D=8 d/thread
// via wave-uniform readfirstlane (s_load W), bv batched 32-deep (VGPR ~52).
__global__ __launch_bounds__(256) void k_linear(
    const float* __restrict__ bout, const int* __restrict__ jlist,
    const float* __restrict__ Wl0, const float* __restrict__ Wl1,
    const float* __restrict__ sc, float* __restrict__ out) {
    const int s  = blockIdx.y >> 2;
    const int dg = blockIdx.y & 3;
    const int jj = threadIdx.x & 63;
    const int wv = threadIdx.x >> 6;
    const int dbase = __builtin_amdgcn_readfirstlane(dg * 32 + wv * 8);
    const int j = blockIdx.x * 64 + jj;
    const float* __restrict__ Wl = (s == 0) ? Wl0 : Wl1;
    const float* __restrict__ brow = bout + (size_t)s * NP + j;

    float acc[8];
#pragma unroll
    for (int k = 0; k < 8; ++k) acc[k] = 0.f;

#pragma unroll 1
    for (int cc0 = 0; cc0 < C_CH; cc0 += 32) {
        float bv[32];
#pragma unroll
        for (int t = 0; t < 32; ++t)
            bv[t] = brow[(size_t)(cc0 + t) * 4 * NP];
#pragma unroll
        for (int t = 0; t < 32; ++t) {
            const float* wrow = Wl + (cc0 + t) * C_CH + dbase;  // scalar addr
#pragma unroll
            for (int k = 0; k < 8; ++k) acc[k] = fmaf(bv[t], wrow[k], acc[k]);
        }
    }

    const int n = jlist[j];
    if (n < 0) return;
    const float inv = 0.08838834764831845f;  // 1/sqrt(128)
#pragma unroll
    for (int k = 0; k < 8; ++k) {
        int d = dbase + k;
        int col = (s == 0) ? d : (128 + d * 3 + (s - 1));
        out[n * 512 + col] = fmaf(acc[k], inv, sc[n * 512 + col]);
    }
}

extern "C" void kernel_launch(void* const* d_in, const int* in_sizes, int n_in,
                              void* d_out, int out_size, void* d_ws, size_t ws_size,
                              hipStream_t stream) {
    const float* x     = (const float*)d_in[0];
    const float* sc    = (const float*)d_in[1];
    const float* attrs = (const float*)d_in[2];
    const float* U3_0 = (const float*)d_in[3];
    const float* U2_0 = (const float*)d_in[4];
    const float* U1_0 = (const float*)d_in[5];
    const float* W3_0 = (const float*)d_in[6];
    const float* W2_0 = (const float*)d_in[7];
    const float* W1_0 = (const float*)d_in[8];
    const float* Wl0  = (const float*)d_in[9];
    const float* U3_1 = (const float*)d_in[10];
    const float* U2_1 = (const float*)d_in[11];
    const float* U1_1 = (const float*)d_in[12];
    const float* W3_1 = (const float*)d_in[13];
    const float* W2_1 = (const float*)d_in[14];
    const float* W1_1 = (const float*)d_in[15];
    const float* Wl1  = (const float*)d_in[16];

    char* ws = (char*)d_ws;
    int* chE     = (int*)(ws + WS_CHE);
    int* chJ     = (int*)(ws + WS_CHJ);
    int* chEnd   = (int*)(ws + WS_CHEND);
    int* jlist   = (int*)(ws + WS_JLIST);
    int* elem    = (int*)(ws + WS_ELEM);
    float* S31   = (float*)(ws + WS_S31);
    float* S30   = (float*)(ws + WS_S30);
    float* S21   = (float*)(ws + WS_S21);
    float* S20   = (float*)(ws + WS_S20);
    float* P     = (float*)(ws + WS_P);
    float* bout  = (float*)(ws + WS_BOUT);

    // L1: sym + elem decode (spread across CUs)
    k_front<<<35, 256, 0, stream>>>(attrs, elem, U3_1, U3_0, U2_1, U2_0,
                                    S31, S30, S21, S20);
    // L2: sort (block 0) || fold P (blocks 1-1280)
    k_sortfold<<<1281, 1024, 0, stream>>>(elem, jlist, chE, chJ, chEnd,
                                          S31, S30, S21, S20, U1_1, U1_0,
                                          W3_1, W3_0, W2_1, W2_0, W1_1, W1_0, P);
    // L3: 219-monomial cubic (s_load coefficients, direct x gather)
    k_poly<<<dim3(128, MAXCHUNK), 256, 0, stream>>>(x, jlist, chE, chJ, chEnd,
                                                    P, bout);
    // L4: channel-mixing linear + residual
    k_linear<<<dim3(NP / 64, 16), 256, 0, stream>>>(bout, jlist, Wl0, Wl1, sc,
                                                    (float*)d_out);
}